// Round 4
// baseline (199.790 us; speedup 1.0000x reference)
//
#include <hip/hip_runtime.h>
#include <hip/hip_bf16.h>
#include <math.h>

// Problem constants (fixed by reference).
constexpr int NVOX = 40000;
constexpr int NQRY = 8192;
constexpr int KK   = 96;
constexpr int CH   = 128;
constexpr int FFD  = 256;
constexpr int VT   = 32;               // voxels per KV block
constexpr int NKV  = NVOX / VT;        // 1250 fused LN+KV blocks (all 8 heads each)
constexpr int NEB  = 24;               // epilogue-weight convert blocks

typedef __attribute__((ext_vector_type(8))) short short8;
typedef __attribute__((ext_vector_type(4))) float float4v;

__device__ inline float bflo(unsigned u) { return __uint_as_float(u << 16); }
__device__ inline float bfhi(unsigned u) { return __uint_as_float(u & 0xffff0000u); }
__device__ inline unsigned short f2bf(float x) {
  union { float f; unsigned u; } a; a.f = x;
  const unsigned r = a.u + 0x7fffu + ((a.u >> 16) & 1u);  // round-to-nearest-even
  return (unsigned short)(r >> 16);
}
__device__ inline unsigned pack2(float lo, float hi) {
  return (unsigned)f2bf(lo) | ((unsigned)f2bf(hi) << 16);
}

// ---------------------------------------------------------------------------
// Kernel 1 (fused prep): KV projection -> VOXEL-MAJOR lines.
//  KVv line (512 B per voxel): [K h0..h7 (16 bf16 each) | V h0..h7].
//  blocks [0, NKV):        32 voxels: LN+relu(key-pos) once -> swizzled LDS;
//                          4 warps x 2 heads KV GEMM via MFMA -> stg -> KVv.
//  blocks [NKV, NKV+24):   epilogue weights -> Eb bf16
//  blocks [NKV+24, +512):  q = relu(qc@q_pos_w.T+b) @ wq.T + bq -> qb f32
// ---------------------------------------------------------------------------
__global__ __launch_bounds__(256) void k_main(
    const float* __restrict__ vfeat, const float* __restrict__ vcoord,
    const float* __restrict__ n1g, const float* __restrict__ n1b,
    const float* __restrict__ kpw, const float* __restrict__ kpb,
    const float* __restrict__ in_w, const float* __restrict__ in_b,
    const float* __restrict__ ow, const float* __restrict__ l1w,
    const float* __restrict__ l2w, const float* __restrict__ fw,
    const float* __restrict__ qcoord,
    const float* __restrict__ qpw, const float* __restrict__ qpb,
    unsigned short* __restrict__ KVv, __hip_bfloat16* __restrict__ Eb,
    float* __restrict__ qout) {
  __shared__ __align__(16) char smem[VT*128*2 + VT*264*2];   // 25088 B
  const int b = blockIdx.x;
  const int t = threadIdx.x;
  if (b < NKV) {
    unsigned short* Gs  = reinterpret_cast<unsigned short*>(smem);            // [32][128] swizzled bf16
    unsigned short* stg = reinterpret_cast<unsigned short*>(smem + VT*128*2); // [32][264]
    const int v0 = b * VT;
    // ---- Phase 1: LN + relu(key-pos), once per voxel (8 lanes/voxel) ----
    {
      const int row = t >> 3;          // 0..31 voxel within tile
      const int q   = t & 7;           // 16-channel group [q*16, q*16+16)
      const int j   = v0 + row;
      const float* vrow = vfeat + (size_t)j * CH + q*16;
      float4 xv[4];
      #pragma unroll
      for (int i = 0; i < 4; i++) xv[i] = reinterpret_cast<const float4*>(vrow)[i];
      float s = 0.0f, ss = 0.0f;
      #pragma unroll
      for (int i = 0; i < 4; i++) {
        s  += xv[i].x + xv[i].y + xv[i].z + xv[i].w;
        ss += xv[i].x*xv[i].x + xv[i].y*xv[i].y + xv[i].z*xv[i].z + xv[i].w*xv[i].w;
      }
      s += __shfl_xor(s, 1);  ss += __shfl_xor(ss, 1);
      s += __shfl_xor(s, 2);  ss += __shfl_xor(ss, 2);
      s += __shfl_xor(s, 4);  ss += __shfl_xor(ss, 4);
      const float mean = s * (1.0f/CH);
      const float var  = ss * (1.0f/CH) - mean*mean;
      const float rstd = 1.0f / sqrtf(var + 1e-5f);
      const float c0 = vcoord[j*3+0], c1 = vcoord[j*3+1], c2 = vcoord[j*3+2];
      #pragma unroll
      for (int i = 0; i < 4; i++) {
        const int ch0 = q*16 + i*4;
        const float4 g4 = *reinterpret_cast<const float4*>(n1g + ch0);
        const float4 b4 = *reinterpret_cast<const float4*>(n1b + ch0);
        const float4 p4 = *reinterpret_cast<const float4*>(kpb + ch0);
        const float4 k0 = *reinterpret_cast<const float4*>(kpw + ch0*3);
        const float4 k1 = *reinterpret_cast<const float4*>(kpw + ch0*3 + 4);
        const float4 k2 = *reinterpret_cast<const float4*>(kpw + ch0*3 + 8);
        float o0 = fmaf((xv[i].x - mean)*rstd, g4.x, b4.x)
                 + fmaxf(fmaf(c0,k0.x, fmaf(c1,k0.y, fmaf(c2,k0.z, p4.x))), 0.0f);
        float o1 = fmaf((xv[i].y - mean)*rstd, g4.y, b4.y)
                 + fmaxf(fmaf(c0,k0.w, fmaf(c1,k1.x, fmaf(c2,k1.y, p4.y))), 0.0f);
        float o2 = fmaf((xv[i].z - mean)*rstd, g4.z, b4.z)
                 + fmaxf(fmaf(c0,k1.z, fmaf(c1,k1.w, fmaf(c2,k2.x, p4.z))), 0.0f);
        float o3 = fmaf((xv[i].w - mean)*rstd, g4.w, b4.w)
                 + fmaxf(fmaf(c0,k2.y, fmaf(c1,k2.z, fmaf(c2,k2.w, p4.w))), 0.0f);
        // Swizzled store: 16B unit = ch0/8, XOR'd with (row&15); half = i&1.
        const int unit = (2*q + (i >> 1)) ^ (row & 15);
        unsigned short* dst = Gs + row*128 + unit*8 + (i & 1)*4;
        *reinterpret_cast<uint2*>(dst) = make_uint2(pack2(o0,o1), pack2(o2,o3));
      }
    }
    __syncthreads();
    // ---- Phase 2: KV GEMM. Warp w handles heads 2w, 2w+1 (K and V each). ----
    {
      const int w    = t >> 6;
      const int lane = t & 63;
      const int col  = lane & 15;
      const int quad = lane >> 4;
      // B fragments (bf16 inline from f32): n = {K h0, V h0, K h1, V h1}.
      short8 bfr[4][4];
      float  bias[4];
      #pragma unroll
      for (int n = 0; n < 4; n++) {
        const int h    = 2*w + (n >> 1);
        const int base = ((n & 1) ? 2*CH : CH) + h*16;
        bias[n] = in_b[base + col];
        const float* wr = in_w + (size_t)(base + col)*CH + quad*8;
        #pragma unroll
        for (int kq = 0; kq < 4; kq++) {
          const float4 a = reinterpret_cast<const float4*>(wr + kq*32)[0];
          const float4 c = reinterpret_cast<const float4*>(wr + kq*32)[1];
          short8 bb;
          bb[0]=(short)f2bf(a.x); bb[1]=(short)f2bf(a.y);
          bb[2]=(short)f2bf(a.z); bb[3]=(short)f2bf(a.w);
          bb[4]=(short)f2bf(c.x); bb[5]=(short)f2bf(c.y);
          bb[6]=(short)f2bf(c.z); bb[7]=(short)f2bf(c.w);
          bfr[n][kq] = bb;
        }
      }
      #pragma unroll
      for (int m = 0; m < 2; m++) {
        short8 af[4];
        #pragma unroll
        for (int kq = 0; kq < 4; kq++) {
          const int unit = (kq*4 + quad) ^ col;   // (row&15)==col for row=m*16+col
          af[kq] = *reinterpret_cast<const short8*>(Gs + (m*16 + col)*128 + unit*8);
        }
        #pragma unroll
        for (int n = 0; n < 4; n++) {
          float4v acc = (float4v){bias[n], bias[n], bias[n], bias[n]};
          #pragma unroll
          for (int kq = 0; kq < 4; kq++)
            acc = __builtin_amdgcn_mfma_f32_16x16x32_bf16(af[kq], bfr[n][kq], acc, 0, 0, 0);
          const int h   = 2*w + (n >> 1);
          const int off = h*32 + (n & 1)*16 + col;
          #pragma unroll
          for (int r = 0; r < 4; r++)
            stg[(m*16 + quad*4 + r)*264 + off] = f2bf(acc[r]);
        }
      }
    }
    __syncthreads();
    // ---- Phase 3: voxel-major lines: [K h0..h7 | V h0..h7] (64 B per thread,
    // 8 threads cover a 512 B line; wave writes 16 KB contiguous). ----
    {
      const int vox    = t >> 3;
      const int c      = t & 7;
      const int kvhalf = c >> 2;          // 0 = K, 1 = V
      const int hp     = (c & 3) * 2;     // head pair base
      const uint4* sA = reinterpret_cast<const uint4*>(stg + vox*264 + hp*32 + kvhalf*16);
      const uint4* sB = reinterpret_cast<const uint4*>(stg + vox*264 + (hp+1)*32 + kvhalf*16);
      uint4* dst = reinterpret_cast<uint4*>(KVv + (size_t)(v0 + vox)*256 + kvhalf*128 + hp*16);
      dst[0] = sA[0]; dst[1] = sA[1]; dst[2] = sB[0]; dst[3] = sB[1];
    }
  } else if (b < NKV + NEB) {
    // epilogue weights -> bf16
    const int idx = b - NKV;
    const int f = (idx * 256 + t) * 16;   // 0..98303
    const float* src;
    __hip_bfloat16* dst = Eb + f;
    if      (f < 16384) src = ow  + f;
    else if (f < 49152) src = l1w + (f - 16384);
    else if (f < 81920) src = l2w + (f - 49152);
    else                src = fw  + (f - 81920);
    float v[16];
    #pragma unroll
    for (int u = 0; u < 4; u++) {
      const float4 fq = *reinterpret_cast<const float4*>(src + u*4);
      v[u*4+0]=fq.x; v[u*4+1]=fq.y; v[u*4+2]=fq.z; v[u*4+3]=fq.w;
    }
    uint4* o = reinterpret_cast<uint4*>(dst);
    o[0] = make_uint4(pack2(v[0],v[1]), pack2(v[2],v[3]),
                      pack2(v[4],v[5]), pack2(v[6],v[7]));
    o[1] = make_uint4(pack2(v[8],v[9]), pack2(v[10],v[11]),
                      pack2(v[12],v[13]), pack2(v[14],v[15]));
  } else {
    // q projection: 16 queries per block.
    float (*qf)[CH] = reinterpret_cast<float (*)[CH]>(smem);
    const int qbase = (b - (NKV + NEB)) * 16;
    #pragma unroll
    for (int i = 0; i < 8; i++) {
      const int e = t + 256*i;
      const int qv = e >> 7, c = e & 127;
      const int qq = qbase + qv;
      const float v = fmaf(qcoord[qq*3+0], qpw[c*3+0],
                      fmaf(qcoord[qq*3+1], qpw[c*3+1],
                      fmaf(qcoord[qq*3+2], qpw[c*3+2], qpb[c])));
      qf[qv][c] = fmaxf(v, 0.0f);
    }
    __syncthreads();
    const int oc = t & 127, half = t >> 7;
    const float* wrow = in_w + (size_t)oc * CH;
    const float bia = in_b[oc];
    float acc[8];
    #pragma unroll
    for (int v = 0; v < 8; v++) acc[v] = bia;
    for (int c = 0; c < CH; c += 4) {
      const float4 w4 = *reinterpret_cast<const float4*>(wrow + c);
      #pragma unroll
      for (int v = 0; v < 8; v++) {
        const float4 g4 = *reinterpret_cast<const float4*>(&qf[half*8+v][c]);
        acc[v] = fmaf(g4.x, w4.x, fmaf(g4.y, w4.y, fmaf(g4.z, w4.z, fmaf(g4.w, w4.w, acc[v]))));
      }
    }
    #pragma unroll
    for (int v = 0; v < 8; v++) qout[(size_t)(qbase + half*8 + v)*CH + oc] = acc[v];
  }
}

// ---------------------------------------------------------------------------
// Kernel 2 (fused attention + epilogue): block = 8 queries x ALL 8 heads.
// Per (q,k): one 256 B K-half line read (8 lanes x 32 B), scores for all
// heads; softmax; V-half pass; shfl-reduced ctx -> csb; then the verified
// MFMA epilogue chain on 16-row tiles (rows 8..15 zero, stores guarded).
// ---------------------------------------------------------------------------
__global__ __launch_bounds__(256) void k_fa(
    const unsigned short* __restrict__ KVv,
    const float* __restrict__ qg, const int* __restrict__ kidx,
    const __hip_bfloat16* __restrict__ Eb,
    const float* __restrict__ ob,
    const float* __restrict__ n2g, const float* __restrict__ n2b,
    const float* __restrict__ l1b, const float* __restrict__ l2b,
    const float* __restrict__ fb,
    float* __restrict__ outp) {
  __shared__ __align__(16) char sm[38144];
  int*            idxb  = reinterpret_cast<int*>(sm);                      // [8][96]
  float*          qsb   = reinterpret_cast<float*>(sm + 3072);             // [8][128]
  float*          scb   = reinterpret_cast<float*>(sm + 7168);             // [8][8][104]
  float*          attnS = reinterpret_cast<float*>(sm + 7168);             // [16][132] (union)
  unsigned short* hb    = reinterpret_cast<unsigned short*>(sm + 15616);   // [16][136] (union)
  unsigned short* a1b   = reinterpret_cast<unsigned short*>(sm + 19968);   // [16][264] (union)
  unsigned short* xb    = reinterpret_cast<unsigned short*>(sm + 28416);   // [16][136] (union)
  unsigned short* csb   = reinterpret_cast<unsigned short*>(sm + 33792);   // [16][136]
  const unsigned short* owb  = reinterpret_cast<const unsigned short*>(Eb);
  const unsigned short* l1wb = owb + 16384;
  const unsigned short* l2wb = owb + 49152;
  const unsigned short* fwb  = owb + 81920;

  const int t   = threadIdx.x;
  const int qn0 = blockIdx.x * 8;

  // ---- stage: indices, q-features; zero csb pad rows ----
  #pragma unroll
  for (int i = 0; i < 3; i++) idxb[t + 256*i] = kidx[(size_t)qn0*KK + t + 256*i];
  #pragma unroll
  for (int i = 0; i < 4; i++) qsb[t + 256*i] = qg[(size_t)qn0*CH + t + 256*i];
  if (t < 128) {
    const int row = 8 + (t >> 4), c = (t & 15) * 8;
    *reinterpret_cast<uint4*>(&csb[row*136 + c]) = make_uint4(0,0,0,0);
  }
  __syncthreads();

  const int warp = t >> 6, lane = t & 63;
  const int q2    = lane >> 5;          // 2 queries per warp
  const int kslot = (lane >> 3) & 3;    // 4 key slots
  const int h     = lane & 7;           // head
  const int q     = warp*2 + q2;        // block-local query 0..7

  float qreg[16];
  #pragma unroll
  for (int d = 0; d < 16; d++) qreg[d] = qsb[q*CH + h*16 + d];

  // ---- K-pass: scores for (q, h, 24 keys of this slot) ----
  #pragma unroll
  for (int it = 0; it < 24; it++) {
    const int k  = kslot + (it << 2);
    const int j0 = idxb[q*KK + k];
    const int j  = (j0 < 0) ? 0 : j0;
    const unsigned short* p = KVv + (size_t)j*256 + h*16;
    const uint4 a = *reinterpret_cast<const uint4*>(p);
    const uint4 bq = *reinterpret_cast<const uint4*>(p + 8);
    float s = 0.0f;
    s = fmaf(qreg[0],  bflo(a.x),  s); s = fmaf(qreg[1],  bfhi(a.x),  s);
    s = fmaf(qreg[2],  bflo(a.y),  s); s = fmaf(qreg[3],  bfhi(a.y),  s);
    s = fmaf(qreg[4],  bflo(a.z),  s); s = fmaf(qreg[5],  bfhi(a.z),  s);
    s = fmaf(qreg[6],  bflo(a.w),  s); s = fmaf(qreg[7],  bfhi(a.w),  s);
    s = fmaf(qreg[8],  bflo(bq.x), s); s = fmaf(qreg[9],  bfhi(bq.x), s);
    s = fmaf(qreg[10], bflo(bq.y), s); s = fmaf(qreg[11], bfhi(bq.y), s);
    s = fmaf(qreg[12], bflo(bq.z), s); s = fmaf(qreg[13], bfhi(bq.z), s);
    s = fmaf(qreg[14], bflo(bq.w), s); s = fmaf(qreg[15], bfhi(bq.w), s);
    scb[(q*8 + h)*104 + k] = (j0 < 0) ? -1e9f : s * 0.25f;
  }
  __syncthreads();

  // ---- softmax: 4 lanes per (q,h) row over 96 keys ----
  {
    const int row  = t >> 2;          // 0..63 = q*8+h
    const int part = t & 3;
    float* sp = scb + row*104;
    float v[24];
    float mx = -3e38f;
    #pragma unroll
    for (int j = 0; j < 24; j++) { v[j] = sp[part + 4*j]; mx = fmaxf(mx, v[j]); }
    mx = fmaxf(mx, __shfl_xor(mx, 1));
    mx = fmaxf(mx, __shfl_xor(mx, 2));
    float sum = 0.0f;
    #pragma unroll
    for (int j = 0; j < 24; j++) { v[j] = __expf(v[j] - mx); sum += v[j]; }
    sum += __shfl_xor(sum, 1);
    sum += __shfl_xor(sum, 2);
    const float rinv = 1.0f / sum;
    #pragma unroll
    for (int j = 0; j < 24; j++) sp[part + 4*j] = v[j] * rinv;
  }
  __syncthreads();

  // ---- V-pass: ctx accumulate, shfl-reduce across key slots -> csb ----
  {
    float acc[16];
    #pragma unroll
    for (int d = 0; d < 16; d++) acc[d] = 0.0f;
    #pragma unroll
    for (int it = 0; it < 24; it++) {
      const int k  = kslot + (it << 2);
      const int j0 = idxb[q*KK + k];
      const int j  = (j0 < 0) ? 0 : j0;
      const float wgt = scb[(q*8 + h)*104 + k];
      const unsigned short* p = KVv + (size_t)j*256 + 128 + h*16;
      const uint4 a = *reinterpret_cast<const uint4*>(p);
      const uint4 bq = *reinterpret_cast<const uint4*>(p + 8);
      acc[0]  = fmaf(wgt, bflo(a.x),  acc[0]);  acc[1]  = fmaf(wgt, bfhi(a.x),  acc[1]);
      acc[2]  = fmaf(wgt, bflo(a.y),  acc[2]);  acc[3]  = fmaf(wgt, bfhi(a.y),  acc[3]);
      acc[4]  = fmaf(wgt, bflo(a.z),  acc[4]);  acc[5]  = fmaf(wgt, bfhi(a.z),  acc[5]);
      acc[6]  = fmaf(wgt, bflo(a.w),  acc[6]);  acc[7]  = fmaf(wgt, bfhi(a.w),  acc[7]);
      acc[8]  = fmaf(wgt, bflo(bq.x), acc[8]);  acc[9]  = fmaf(wgt, bfhi(bq.x), acc[9]);
      acc[10] = fmaf(wgt, bflo(bq.y), acc[10]); acc[11] = fmaf(wgt, bfhi(bq.y), acc[11]);
      acc[12] = fmaf(wgt, bflo(bq.z), acc[12]); acc[13] = fmaf(wgt, bfhi(bq.z), acc[13]);
      acc[14] = fmaf(wgt, bflo(bq.w), acc[14]); acc[15] = fmaf(wgt, bfhi(bq.w), acc[15]);
    }
    #pragma unroll
    for (int d = 0; d < 16; d++) {
      acc[d] += __shfl_xor(acc[d], 8);
      acc[d] += __shfl_xor(acc[d], 16);
    }
    if ((lane & 24) == 0) {   // kslot == 0 holds the full (q,h) ctx
      unsigned short* cp = csb + q*136 + h*16;
      *reinterpret_cast<uint4*>(cp) =
          make_uint4(pack2(acc[0],acc[1]),  pack2(acc[2],acc[3]),
                     pack2(acc[4],acc[5]),  pack2(acc[6],acc[7]));
      *reinterpret_cast<uint4*>(cp + 8) =
          make_uint4(pack2(acc[8],acc[9]),  pack2(acc[10],acc[11]),
                     pack2(acc[12],acc[13]), pack2(acc[14],acc[15]));
    }
  }
  __syncthreads();

  // ---- epilogue (verified k_epi chain; rows 8..15 are zero padding) ----
  const int w    = warp;
  const int col  = lane & 15;
  const int quad = lane >> 4;
  {
    short8 af[4];
    #pragma unroll
    for (int kq = 0; kq < 4; kq++)
      af[kq] = *reinterpret_cast<const short8*>(&csb[col*136 + quad*8 + kq*32]);
    #pragma unroll
    for (int j = 0; j < 2; j++) {
      const int n0 = w*32 + j*16;
      const float bia = ob[n0 + col];
      float4v acc = (float4v){bia, bia, bia, bia};
      #pragma unroll
      for (int kq = 0; kq < 4; kq++) {
        const short8 bf = *reinterpret_cast<const short8*>(
            owb + (size_t)(n0 + col)*CH + kq*32 + quad*8);
        acc = __builtin_amdgcn_mfma_f32_16x16x32_bf16(af[kq], bf, acc, 0, 0, 0);
      }
      #pragma unroll
      for (int r = 0; r < 4; r++) attnS[(quad*4 + r)*132 + n0 + col] = acc[r];
    }
  }
  __syncthreads();
  {
    const int row = t >> 4, l = t & 15;
    float s = 0.0f, ss = 0.0f;
    #pragma unroll
    for (int c = l; c < CH; c += 16) { const float x = attnS[row*132 + c]; s += x; ss += x*x; }
    #pragma unroll
    for (int m = 8; m >= 1; m >>= 1) { s += __shfl_xor(s, m); ss += __shfl_xor(ss, m); }
    const float mean = s * (1.0f/CH);
    const float var  = ss * (1.0f/CH) - mean*mean;
    const float rstd = 1.0f / sqrtf(var + 1e-5f);
    #pragma unroll
    for (int c = l; c < CH; c += 16)
      hb[row*136 + c] = f2bf((attnS[row*132 + c] - mean) * rstd * n2g[c] + n2b[c]);
  }
  __syncthreads();
  {
    short8 af[4];
    #pragma unroll
    for (int kq = 0; kq < 4; kq++)
      af[kq] = *reinterpret_cast<const short8*>(&hb[col*136 + quad*8 + kq*32]);
    #pragma unroll
    for (int j = 0; j < 4; j++) {
      const int n0 = w*64 + j*16;
      const float bia = l1b[n0 + col];
      float4v acc = (float4v){bia, bia, bia, bia};
      #pragma unroll
      for (int kq = 0; kq < 4; kq++) {
        const short8 bf = *reinterpret_cast<const short8*>(
            l1wb + (size_t)(n0 + col)*CH + kq*32 + quad*8);
        acc = __builtin_amdgcn_mfma_f32_16x16x32_bf16(af[kq], bf, acc, 0, 0, 0);
      }
      #pragma unroll
      for (int r = 0; r < 4; r++)
        a1b[(quad*4 + r)*264 + n0 + col] = f2bf(fmaxf(acc[r], 0.0f));
    }
  }
  __syncthreads();
  {
    short8 af[8];
    #pragma unroll
    for (int kq = 0; kq < 8; kq++)
      af[kq] = *reinterpret_cast<const short8*>(&a1b[col*264 + quad*8 + kq*32]);
    #pragma unroll
    for (int j = 0; j < 2; j++) {
      const int n0 = w*32 + j*16;
      const float bia = l2b[n0 + col];
      float4v acc = (float4v){bia, bia, bia, bia};
      #pragma unroll
      for (int kq = 0; kq < 8; kq++) {
        const short8 bf = *reinterpret_cast<const short8*>(
            l2wb + (size_t)(n0 + col)*FFD + kq*32 + quad*8);
        acc = __builtin_amdgcn_mfma_f32_16x16x32_bf16(af[kq], bf, acc, 0, 0, 0);
      }
      #pragma unroll
      for (int r = 0; r < 4; r++)
        xb[(quad*4 + r)*136 + n0 + col] = f2bf(acc[r] + attnS[(quad*4 + r)*132 + n0 + col]);
    }
  }
  __syncthreads();
  {
    short8 af[4];
    #pragma unroll
    for (int kq = 0; kq < 4; kq++)
      af[kq] = *reinterpret_cast<const short8*>(&xb[col*136 + quad*8 + kq*32]);
    #pragma unroll
    for (int j = 0; j < 2; j++) {
      const int n0 = w*32 + j*16;
      const float bia = fb[n0 + col];
      float4v acc = (float4v){bia, bia, bia, bia};
      #pragma unroll
      for (int kq = 0; kq < 4; kq++) {
        const short8 bf = *reinterpret_cast<const short8*>(
            fwb + (size_t)(n0 + col)*CH + kq*32 + quad*8);
        acc = __builtin_amdgcn_mfma_f32_16x16x32_bf16(af[kq], bf, acc, 0, 0, 0);
      }
      #pragma unroll
      for (int r = 0; r < 4; r++) {
        const int row = quad*4 + r;
        if (row < 8)
          outp[(size_t)(qn0 + row)*CH + n0 + col] = fmaxf(acc[r], 0.0f);
      }
    }
  }
}

// ---------------------------------------------------------------------------
extern "C" void kernel_launch(void* const* d_in, const int* in_sizes, int n_in,
                              void* d_out, int out_size, void* d_ws, size_t ws_size,
                              hipStream_t stream) {
  const float* vfeat  = (const float*)d_in[0];
  const float* vcoord = (const float*)d_in[1];
  const float* qcoord = (const float*)d_in[2];
  const int*   kidx   = (const int*)  d_in[3];
  const float* n1g    = (const float*)d_in[4];
  const float* n1b    = (const float*)d_in[5];
  const float* qpw    = (const float*)d_in[6];
  const float* qpb    = (const float*)d_in[7];
  const float* kpw    = (const float*)d_in[8];
  const float* kpb    = (const float*)d_in[9];
  const float* in_w   = (const float*)d_in[10];
  const float* in_b   = (const float*)d_in[11];
  const float* out_w  = (const float*)d_in[12];
  const float* out_b  = (const float*)d_in[13];
  const float* n2g    = (const float*)d_in[14];
  const float* n2b    = (const float*)d_in[15];
  const float* l1w    = (const float*)d_in[16];
  const float* l1b    = (const float*)d_in[17];
  const float* l2w    = (const float*)d_in[18];
  const float* l2b    = (const float*)d_in[19];
  const float* fw     = (const float*)d_in[20];
  const float* fb     = (const float*)d_in[21];
  float* out = (float*)d_out;

  unsigned short* KVv = (unsigned short*)d_ws;               // NVOX*256 ush (20.5 MB)
  __hip_bfloat16* Eb = (__hip_bfloat16*)(KVv + (size_t)NVOX*256);  // 98304 bf16 epi weights
  float* qb = (float*)(Eb + 98304);                          // NQRY*CH f32

  k_main<<<NKV + NEB + NQRY/16, 256, 0, stream>>>(
      vfeat, vcoord, n1g, n1b, kpw, kpb, in_w, in_b,
      out_w, l1w, l2w, fw, qcoord, qpw, qpb, KVv, Eb, qb);
  k_fa<<<NQRY/8, 256, 0, stream>>>(
      KVv, qb, kidx, Eb, out_b, n2g, n2b, l1b, l2b, fb, out);
}